// Round 5
// baseline (437.289 us; speedup 1.0000x reference)
//
#include <hip/hip_runtime.h>
#include <hip/hip_bf16.h>

// RankMixerNSTokenizer: embed/pool -> LHUC (silu GEMM, sigmoid GEMM, gate) ->
// per-token proj GEMM + fused LayerNorm.
// B=4096, NS=40, NM=8, L=8, V=10000, D=64, T=16, DM=512, TOTAL=3072, CHUNK=192.
//
//   K0 transpose_all:  w1->w1t[768][3072], w2->w2t[3072][768], proj_w->pwt[16][512][192]
//   K1 embed:          int_feats + tables -> catb bf16 [4096][3072]  (float4 gathers)
//   K2 gemm<64,128>:   hb = silu(catb @ w1t^T + b1)            [4096][768]   384 blk
//   K3 gemm<128,256>:  xb = catb * sigmoid(hb @ w2t^T + b2)*2  [4096][3072]  384 blk
//      K3 wave tile 128x64 (MF=8,NF=4): 12 ds_read_b128 per 32 MFMA.
//   K4 proj_ln:        out = LN(xb_t @ pwt[t]^T + pb) * g + b  [4096][16][512] f32
// All GEMM-ish grids XCD-swizzled (8 XCDs, grids are multiples of 8).

typedef unsigned short u16;
typedef unsigned int u32;
typedef __attribute__((ext_vector_type(8))) short s16x8;   // 8 bf16 (4 VGPRs)
typedef __attribute__((ext_vector_type(4))) float f32x4;

#define NSF 40
#define NMF 8
#define LLEN 8
#define VROWS 10001
#define DD 64
#define TT 16
#define DMOD 512
#define TOTAL 3072
#define CHUNKC 192
#define NFEAT 104

__device__ __forceinline__ u16 f2bf(float f) {
  __hip_bfloat16 h = __float2bfloat16(f);
  return *reinterpret_cast<u16*>(&h);
}
__device__ __forceinline__ float bf2f(u16 u) {
  __hip_bfloat16 h;
  *reinterpret_cast<u16*>(&h) = u;
  return __bfloat162float(h);
}

__device__ __forceinline__ void gll16(const u16* g, u16* l) {
  // async global->LDS, 16B per lane; LDS dest = wave-uniform base + lane*16
  __builtin_amdgcn_global_load_lds((const __attribute__((address_space(1))) void*)g,
                                   (__attribute__((address_space(3))) void*)l, 16, 0, 0);
}

// ---------------- K0: all weight transposes in one launch --------------------
// flat grid: [0,2304) w1 (24x96), [2304,4608) w2 (96x24), [4608,6144) pw (16x6 x16 t)
__global__ void transpose_all_kernel(const float* __restrict__ w1, u16* __restrict__ w1t,
                                     const float* __restrict__ w2, u16* __restrict__ w2t,
                                     const float* __restrict__ pw, u16* __restrict__ pwt) {
  __shared__ float tile[32][33];
  int id = blockIdx.x;
  const float* src; u16* dst; int R, C, bx, by;
  if (id < 2304)      { src = w1; dst = w1t; R = 3072; C = 768;  bx = id % 24; by = id / 24; }
  else if (id < 4608) { int l = id - 2304; src = w2; dst = w2t; R = 768; C = 3072; bx = l % 96; by = l / 96; }
  else                { int l = id - 4608; int t = l / 96; int r2 = l % 96;
                        src = pw + (long)t * CHUNKC * DMOD; dst = pwt + (long)t * DMOD * CHUNKC;
                        R = CHUNKC; C = DMOD; bx = r2 % 16; by = r2 / 16; }
  int c0 = bx * 32, r0 = by * 32;
#pragma unroll
  for (int i = 0; i < 32; i += 8)
    tile[threadIdx.y + i][threadIdx.x] = src[(long)(r0 + threadIdx.y + i) * C + c0 + threadIdx.x];
  __syncthreads();
#pragma unroll
  for (int i = 0; i < 32; i += 8)
    dst[(long)(c0 + threadIdx.y + i) * R + r0 + threadIdx.x] = f2bf(tile[threadIdx.x][threadIdx.y + i]);
}

// ---------------- K1: embedding gather + masked mean pool -> catb bf16 --------
// 16 lanes per feature row, float4 (16B) gathers.
__global__ __launch_bounds__(256) void embed_kernel(const int* __restrict__ feats,
                                                    const float* __restrict__ tabS,
                                                    const float* __restrict__ tabM,
                                                    u16* __restrict__ catb) {
  int b = blockIdx.x;
  int tid = threadIdx.x;
  int d4 = tid & 15;  // float4 index within D=64
  int g = tid >> 4;   // 0..15
  const int* fr = feats + (long)b * NFEAT;
  u16* crow = catb + (long)b * TOTAL;

  // singles: feature f handled by group g == f%16
  for (int f = g; f < NSF; f += 16) {
    int idx = fr[f];
    float4 v = make_float4(0.f, 0.f, 0.f, 0.f);
    if (idx) v = *reinterpret_cast<const float4*>(tabS + ((long)f * VROWS + idx) * DD + d4 * 4);
    ushort4 pk = {f2bf(v.x), f2bf(v.y), f2bf(v.z), f2bf(v.w)};
    *reinterpret_cast<ushort4*>(crow + f * DD + d4 * 4) = pk;
  }
  // multi: two groups per feature m (half = l subrange), combine via shfl
  int m = g >> 1, half = g & 1;
  float sx = 0.f, sy = 0.f, sz = 0.f, sw = 0.f, cnt = 0.f;
#pragma unroll
  for (int l = 0; l < 4; l++) {
    int idx = fr[NSF + m * LLEN + half * 4 + l];
    if (idx) {
      float4 e = *reinterpret_cast<const float4*>(tabM + ((long)m * VROWS + idx) * DD + d4 * 4);
      sx += e.x; sy += e.y; sz += e.z; sw += e.w; cnt += 1.f;
    }
  }
  sx += __shfl_xor(sx, 16, 64);
  sy += __shfl_xor(sy, 16, 64);
  sz += __shfl_xor(sz, 16, 64);
  sw += __shfl_xor(sw, 16, 64);
  cnt += __shfl_xor(cnt, 16, 64);
  if (!half) {
    float inv = 1.f / fmaxf(cnt, 1.f);
    ushort4 pk = {f2bf(sx * inv), f2bf(sy * inv), f2bf(sz * inv), f2bf(sw * inv)};
    *reinterpret_cast<ushort4*>(crow + NSF * DD + m * DD + d4 * 4) = pk;
  }
}

// ---------------- K2/K3: MFMA GEMM, BM x BN, BK=32, 256 threads --------------
// A [M][K] bf16 row-major, Bt [N][K] bf16 row-major (K-major), out bf16.
// Wave layout: WCOL = 4 (BN>=256), 2 (BN>=128), else 1; WROW = 4/WCOL.
// EPI 0: out = silu(z + bias);  EPI 1: out = bf(aux) * sigmoid(z + bias) * 2
template <int N, int K, int BM, int BN, int EPI>
__global__ __launch_bounds__(256) void gemm_kernel(const u16* __restrict__ A,
                                                   const u16* __restrict__ Bt,
                                                   const float* __restrict__ bias,
                                                   const u16* __restrict__ aux,
                                                   u16* __restrict__ Out) {
  constexpr int WCOL = (BN >= 256) ? 4 : (BN >= 128) ? 2 : 1;
  constexpr int WROW = 4 / WCOL;
  constexpr int MF = (BM / WROW) / 16;
  constexpr int NF = (BN / WCOL) / 16;
  constexpr int NT = K / 32;

  __shared__ u16 lA[2][BM * 32];
  __shared__ u16 lB[2][BN * 32];

  const int tid = threadIdx.x;
  const int w = tid >> 6;
  const int lane = tid & 63;
  const int l15 = lane & 15, hi = lane >> 4;
  const int wr = w / WCOL, wc = w % WCOL;

  // XCD-aware swizzle (bijective: nblk % 8 == 0 for all our grids)
  const int nblk = gridDim.x * gridDim.y;
  const int lid = blockIdx.x + gridDim.x * blockIdx.y;
  const int sw = (lid & 7) * (nblk >> 3) + (lid >> 3);
  const int m0 = (sw / gridDim.x) * BM, n0 = (sw % gridDim.x) * BN;

  f32x4 acc[MF][NF];
#pragma unroll
  for (int m = 0; m < MF; m++)
#pragma unroll
    for (int n = 0; n < NF; n++) acc[m][n] = (f32x4){0.f, 0.f, 0.f, 0.f};

  const int srow = tid >> 2;        // 0..63
  const int sc8 = (tid & 3) * 8;    // k sub-offset

  auto stage = [&](int buf, int t) {
    const u16* Ab = A + (long)m0 * K + t * 32;
    const u16* Bb = Bt + (long)n0 * K + t * 32;
#pragma unroll
    for (int i = 0; i < BM / 64; i++)
      gll16(Ab + (long)(i * 64 + srow) * K + sc8, &lA[buf][(i * 256 + w * 64) * 8]);
#pragma unroll
    for (int i = 0; i < BN / 64; i++)
      gll16(Bb + (long)(i * 64 + srow) * K + sc8, &lB[buf][(i * 256 + w * 64) * 8]);
  };

  stage(0, 0);
  __syncthreads();

#pragma unroll 2
  for (int t = 0; t < NT; t++) {
    int buf = t & 1;
    if (t + 1 < NT) stage(buf ^ 1, t + 1);
    s16x8 af[MF], bf[NF];
#pragma unroll
    for (int m = 0; m < MF; m++)
      af[m] = *reinterpret_cast<const s16x8*>(&lA[buf][(wr * (MF * 16) + m * 16 + l15) * 32 + hi * 8]);
#pragma unroll
    for (int n = 0; n < NF; n++)
      bf[n] = *reinterpret_cast<const s16x8*>(&lB[buf][(wc * (NF * 16) + n * 16 + l15) * 32 + hi * 8]);
#pragma unroll
    for (int m = 0; m < MF; m++)
#pragma unroll
      for (int n = 0; n < NF; n++)
        acc[m][n] = __builtin_amdgcn_mfma_f32_16x16x32_bf16(af[m], bf[n], acc[m][n], 0, 0, 0);
    __syncthreads();
  }

#pragma unroll
  for (int n = 0; n < NF; n++) {
    int col = n0 + wc * (NF * 16) + n * 16 + l15;
    float bs = bias[col];
#pragma unroll
    for (int m = 0; m < MF; m++) {
      int rbase = m0 + wr * (MF * 16) + m * 16 + hi * 4;
#pragma unroll
      for (int j = 0; j < 4; j++) {
        int row = rbase + j;
        float z = acc[m][n][j] + bs;
        float o;
        if (EPI == 0) {
          o = z / (1.f + __expf(-z));               // silu
        } else {
          float gs = 1.f / (1.f + __expf(-z));      // sigmoid
          float xv = bf2f(aux[(long)row * N + col]);
          o = xv * gs * 2.f;
        }
        Out[(long)row * N + col] = f2bf(o);
      }
    }
  }
}

// ---------------- K4: per-token proj (K=192) + fused LayerNorm ---------------
// Tiled GEMM: BM=64 rows x BN=512 cols (full LN row), BK=32 double-buffered,
// 512 threads = 8 waves as 2M x 4N. Wave tile 32x128 (MF=2, NF=8).
// Both operands staged via global_load_lds (coalesced). LN fused in epilogue.
__global__ __launch_bounds__(512) void proj_ln_kernel(const u16* __restrict__ xb,
                                                      const u16* __restrict__ pwt,
                                                      const float* __restrict__ pb,
                                                      const float* __restrict__ lng,
                                                      const float* __restrict__ lnb,
                                                      float* __restrict__ out) {
  __shared__ u16 lA[2][64 * 32];    //  8 KB
  __shared__ u16 lB[2][512 * 32];   // 64 KB
  __shared__ float sred[64][4][2];  //  2 KB  [row][n-wave][sum,sumsq]

  const int tid = threadIdx.x;
  const int w = tid >> 6, lane = tid & 63;
  const int l15 = lane & 15, hi = lane >> 4;
  const int wr = w >> 2, wc = w & 3;    // 2M x 4N

  // XCD swizzle: same-t blocks land on the same XCD (share pwt[t] in L2)
  const int lid = blockIdx.x + gridDim.x * blockIdx.y;   // gridDim = (64, 16)
  const int sw = (lid & 7) * ((gridDim.x * gridDim.y) >> 3) + (lid >> 3);
  const int t = sw / gridDim.x;
  const int m0 = (sw % gridDim.x) * 64;

  const u16* Ab = xb + (long)m0 * TOTAL + t * CHUNKC;   // row stride TOTAL
  const u16* Bb = pwt + (long)t * DMOD * CHUNKC;        // row stride CHUNKC

  const int srow = tid >> 2;       // 0..127
  const int sc8 = (tid & 3) * 8;

  auto stage = [&](int buf, int kt) {
    if (w < 4)  // A tile: 64 rows x 32 k = 256 chunks of 16B (waves 0-3)
      gll16(Ab + (long)srow * TOTAL + kt * 32 + sc8, &lA[buf][w * 512]);
#pragma unroll
    for (int i = 0; i < 4; i++)  // B tile: 512 rows x 32 k
      gll16(Bb + (long)(i * 128 + srow) * CHUNKC + kt * 32 + sc8,
            &lB[buf][i * 4096 + w * 512]);
  };

  f32x4 acc[2][8];
#pragma unroll
  for (int m = 0; m < 2; m++)
#pragma unroll
    for (int n = 0; n < 8; n++) acc[m][n] = (f32x4){0.f, 0.f, 0.f, 0.f};

  stage(0, 0);
  __syncthreads();

#pragma unroll
  for (int kt = 0; kt < 6; kt++) {
    int buf = kt & 1;
    if (kt + 1 < 6) stage(buf ^ 1, kt + 1);
    s16x8 af[2], bfr[8];
#pragma unroll
    for (int m = 0; m < 2; m++)
      af[m] = *reinterpret_cast<const s16x8*>(&lA[buf][(wr * 32 + m * 16 + l15) * 32 + hi * 8]);
#pragma unroll
    for (int n = 0; n < 8; n++)
      bfr[n] = *reinterpret_cast<const s16x8*>(&lB[buf][(wc * 128 + n * 16 + l15) * 32 + hi * 8]);
#pragma unroll
    for (int m = 0; m < 2; m++)
#pragma unroll
      for (int n = 0; n < 8; n++)
        acc[m][n] = __builtin_amdgcn_mfma_f32_16x16x32_bf16(af[m], bfr[n], acc[m][n], 0, 0, 0);
    __syncthreads();
  }

  // bias + per-row partial stats; lane owns rows r = wr*32 + m*16 + hi*4 + j
  float sum[2][4], sq[2][4];
#pragma unroll
  for (int m = 0; m < 2; m++)
#pragma unroll
    for (int j = 0; j < 4; j++) { sum[m][j] = 0.f; sq[m][j] = 0.f; }

#pragma unroll
  for (int n = 0; n < 8; n++) {
    float bs = pb[t * DMOD + wc * 128 + n * 16 + l15];
#pragma unroll
    for (int m = 0; m < 2; m++)
#pragma unroll
      for (int j = 0; j < 4; j++) {
        float v = acc[m][n][j] + bs;
        acc[m][n][j] = v;
        sum[m][j] += v;
        sq[m][j] += v * v;
      }
  }
#pragma unroll
  for (int m = 0; m < 2; m++)
#pragma unroll
    for (int j = 0; j < 4; j++) {
#pragma unroll
      for (int o = 1; o < 16; o <<= 1) {
        sum[m][j] += __shfl_xor(sum[m][j], o, 64);
        sq[m][j] += __shfl_xor(sq[m][j], o, 64);
      }
    }
  if (l15 == 0) {
#pragma unroll
    for (int m = 0; m < 2; m++)
#pragma unroll
      for (int j = 0; j < 4; j++) {
        int r = wr * 32 + m * 16 + hi * 4 + j;
        sred[r][wc][0] = sum[m][j];
        sred[r][wc][1] = sq[m][j];
      }
  }
  __syncthreads();

  float mean[2][4], rstd[2][4];
#pragma unroll
  for (int m = 0; m < 2; m++)
#pragma unroll
    for (int j = 0; j < 4; j++) {
      int r = wr * 32 + m * 16 + hi * 4 + j;
      float s = sred[r][0][0] + sred[r][1][0] + sred[r][2][0] + sred[r][3][0];
      float q = sred[r][0][1] + sred[r][1][1] + sred[r][2][1] + sred[r][3][1];
      float mu = s * (1.f / 512.f);
      float var = q * (1.f / 512.f) - mu * mu;
      mean[m][j] = mu;
      rstd[m][j] = rsqrtf(var + 1e-5f);
    }
#pragma unroll
  for (int n = 0; n < 8; n++) {
    int c = wc * 128 + n * 16 + l15;
    float g = lng[t * DMOD + c], bb = lnb[t * DMOD + c];
#pragma unroll
    for (int m = 0; m < 2; m++)
#pragma unroll
      for (int j = 0; j < 4; j++) {
        int r = wr * 32 + m * 16 + hi * 4 + j;
        float o = (acc[m][n][j] - mean[m][j]) * rstd[m][j] * g + bb;
        out[((long)(m0 + r) * TT + t) * DMOD + c] = o;
      }
  }
}

// -----------------------------------------------------------------------------
extern "C" void kernel_launch(void* const* d_in, const int* in_sizes, int n_in,
                              void* d_out, int out_size, void* d_ws, size_t ws_size,
                              hipStream_t stream) {
  const int* feats = (const int*)d_in[0];
  const float* embS = (const float*)d_in[1];
  const float* embM = (const float*)d_in[2];
  const float* w1 = (const float*)d_in[3];
  const float* b1 = (const float*)d_in[4];
  const float* w2 = (const float*)d_in[5];
  const float* b2 = (const float*)d_in[6];
  const float* pw = (const float*)d_in[7];
  const float* pb = (const float*)d_in[8];
  const float* lng = (const float*)d_in[9];
  const float* lnb = (const float*)d_in[10];
  float* out = (float*)d_out;

  char* p = (char*)d_ws;
  u16* catb = (u16*)p; p += (size_t)4096 * 3072 * 2;   // 25.2 MB
  u16* hb   = (u16*)p; p += (size_t)4096 * 768 * 2;    //  6.3 MB
  u16* xb   = (u16*)p; p += (size_t)4096 * 3072 * 2;   // 25.2 MB
  u16* w1t  = (u16*)p; p += (size_t)768 * 3072 * 2;    //  4.7 MB
  u16* w2t  = (u16*)p; p += (size_t)3072 * 768 * 2;    //  4.7 MB
  u16* pwt  = (u16*)p; p += (size_t)16 * 512 * 192 * 2;//  3.1 MB  (total ~69 MB)

  // K0: all weight transposes (re-run every call: ws is re-poisoned)
  transpose_all_kernel<<<6144, dim3(32, 8), 0, stream>>>(w1, w1t, w2, w2t, pw, pwt);

  // K1: embedding + pooling
  embed_kernel<<<4096, 256, 0, stream>>>(feats, embS, embM, catb);

  // K2: h = silu(cat @ w1 + b1)    M=4096 N=768 K=3072 -> 384 blocks (1.5/CU)
  gemm_kernel<768, 3072, 64, 128, 0><<<dim3(768 / 128, 4096 / 64), 256, 0, stream>>>(
      catb, w1t, b1, nullptr, hb);

  // K3: x = cat * sigmoid(h @ w2 + b2)   M=4096 N=3072 K=768 -> 384 blocks
  // wave tile 128x64: MF=8, NF=4 -> 12 ds_read_b128 per 32 MFMA
  gemm_kernel<3072, 768, 128, 256, 1><<<dim3(3072 / 256, 4096 / 128), 256, 0, stream>>>(
      hb, w2t, b2, catb, xb);

  // K4: per-token proj + LN  (64 rows x full 512-col row per block) -> 1024 blocks
  proj_ln_kernel<<<dim3(4096 / 64, 16), 512, 0, stream>>>(xb, pwt, pb, lng, lnb, out);
}

// Round 6
// 411.996 us; speedup vs baseline: 1.0614x; 1.0614x over previous
//
#include <hip/hip_runtime.h>
#include <hip/hip_bf16.h>

// RankMixerNSTokenizer: embed/pool -> LHUC (silu GEMM, sigmoid GEMM, gate) ->
// per-token proj GEMM + fused LayerNorm.
// B=4096, NS=40, NM=8, L=8, V=10000, D=64, T=16, DM=512, TOTAL=3072, CHUNK=192.
//
//   K0 transpose_all:  w1->w1t[768][3072], w2->w2t[3072][768], proj_w->pwt[16][512][192]
//   K1 embed:          int_feats + tables -> catb bf16 [4096][3072]  (float4 gathers)
//   K2 gemm<64,64,BK64>:   hb = silu(catb @ w1t^T + b1)            [4096][768]   768 blk
//   K3 gemm<128,128,BK32>: xb = catb * sigmoid(hb @ w2t^T + b2)*2  [4096][3072]  768 blk
//   K4 proj_ln:        out = LN(xb_t @ pwt[t]^T + pb) * g + b  [4096][16][512] f32
// No XCD swizzle (round-2 best config; reused operands are L3-resident).

typedef unsigned short u16;
typedef unsigned int u32;
typedef __attribute__((ext_vector_type(8))) short s16x8;   // 8 bf16 (4 VGPRs)
typedef __attribute__((ext_vector_type(4))) float f32x4;

#define NSF 40
#define NMF 8
#define LLEN 8
#define VROWS 10001
#define DD 64
#define TT 16
#define DMOD 512
#define TOTAL 3072
#define CHUNKC 192
#define NFEAT 104

__device__ __forceinline__ u16 f2bf(float f) {
  __hip_bfloat16 h = __float2bfloat16(f);
  return *reinterpret_cast<u16*>(&h);
}
__device__ __forceinline__ float bf2f(u16 u) {
  __hip_bfloat16 h;
  *reinterpret_cast<u16*>(&h) = u;
  return __bfloat162float(h);
}

__device__ __forceinline__ void gll16(const u16* g, u16* l) {
  // async global->LDS, 16B per lane; LDS dest = wave-uniform base + lane*16
  __builtin_amdgcn_global_load_lds((const __attribute__((address_space(1))) void*)g,
                                   (__attribute__((address_space(3))) void*)l, 16, 0, 0);
}

// ---------------- K0: all weight transposes in one launch --------------------
// flat grid: [0,2304) w1 (24x96), [2304,4608) w2 (96x24), [4608,6144) pw (16x6 x16 t)
__global__ void transpose_all_kernel(const float* __restrict__ w1, u16* __restrict__ w1t,
                                     const float* __restrict__ w2, u16* __restrict__ w2t,
                                     const float* __restrict__ pw, u16* __restrict__ pwt) {
  __shared__ float tile[32][33];
  int id = blockIdx.x;
  const float* src; u16* dst; int R, C, bx, by;
  if (id < 2304)      { src = w1; dst = w1t; R = 3072; C = 768;  bx = id % 24; by = id / 24; }
  else if (id < 4608) { int l = id - 2304; src = w2; dst = w2t; R = 768; C = 3072; bx = l % 96; by = l / 96; }
  else                { int l = id - 4608; int t = l / 96; int r2 = l % 96;
                        src = pw + (long)t * CHUNKC * DMOD; dst = pwt + (long)t * DMOD * CHUNKC;
                        R = CHUNKC; C = DMOD; bx = r2 % 16; by = r2 / 16; }
  int c0 = bx * 32, r0 = by * 32;
#pragma unroll
  for (int i = 0; i < 32; i += 8)
    tile[threadIdx.y + i][threadIdx.x] = src[(long)(r0 + threadIdx.y + i) * C + c0 + threadIdx.x];
  __syncthreads();
#pragma unroll
  for (int i = 0; i < 32; i += 8)
    dst[(long)(c0 + threadIdx.y + i) * R + r0 + threadIdx.x] = f2bf(tile[threadIdx.x][threadIdx.y + i]);
}

// ---------------- K1: embedding gather + masked mean pool -> catb bf16 --------
// 16 lanes per feature row, float4 (16B) gathers.
__global__ __launch_bounds__(256) void embed_kernel(const int* __restrict__ feats,
                                                    const float* __restrict__ tabS,
                                                    const float* __restrict__ tabM,
                                                    u16* __restrict__ catb) {
  int b = blockIdx.x;
  int tid = threadIdx.x;
  int d4 = tid & 15;  // float4 index within D=64
  int g = tid >> 4;   // 0..15
  const int* fr = feats + (long)b * NFEAT;
  u16* crow = catb + (long)b * TOTAL;

  // singles: feature f handled by group g == f%16
  for (int f = g; f < NSF; f += 16) {
    int idx = fr[f];
    float4 v = make_float4(0.f, 0.f, 0.f, 0.f);
    if (idx) v = *reinterpret_cast<const float4*>(tabS + ((long)f * VROWS + idx) * DD + d4 * 4);
    ushort4 pk = {f2bf(v.x), f2bf(v.y), f2bf(v.z), f2bf(v.w)};
    *reinterpret_cast<ushort4*>(crow + f * DD + d4 * 4) = pk;
  }
  // multi: two groups per feature m (half = l subrange), combine via shfl
  int m = g >> 1, half = g & 1;
  float sx = 0.f, sy = 0.f, sz = 0.f, sw = 0.f, cnt = 0.f;
#pragma unroll
  for (int l = 0; l < 4; l++) {
    int idx = fr[NSF + m * LLEN + half * 4 + l];
    if (idx) {
      float4 e = *reinterpret_cast<const float4*>(tabM + ((long)m * VROWS + idx) * DD + d4 * 4);
      sx += e.x; sy += e.y; sz += e.z; sw += e.w; cnt += 1.f;
    }
  }
  sx += __shfl_xor(sx, 16, 64);
  sy += __shfl_xor(sy, 16, 64);
  sz += __shfl_xor(sz, 16, 64);
  sw += __shfl_xor(sw, 16, 64);
  cnt += __shfl_xor(cnt, 16, 64);
  if (!half) {
    float inv = 1.f / fmaxf(cnt, 1.f);
    ushort4 pk = {f2bf(sx * inv), f2bf(sy * inv), f2bf(sz * inv), f2bf(sw * inv)};
    *reinterpret_cast<ushort4*>(crow + NSF * DD + m * DD + d4 * 4) = pk;
  }
}

// ---------------- K2/K3: MFMA GEMM, BM x BN, BK in {32,64}, 256 threads ------
// A [M][K] bf16 row-major, Bt [N][K] bf16 row-major (K-major), out bf16.
// Wave layout: WCOL = 2 if BN>=128 else 1; WROW = 4/WCOL.
// Staging: 256 threads x 8 elems = 2048 elems/pass => RPP = 2048/BK rows/pass.
// Thread (w,l) writes LDS [row][BK] at linear offset w*512 + l*8 (proof: with
// row = tid/(BK/8), off = row*BK + (tid%(BK/8))*8 = tid*8). gll16 dest base is
// wave-uniform (w*512); per-lane global src carries the row/k split.
// EPI 0: out = silu(z + bias);  EPI 1: out = bf(aux) * sigmoid(z + bias) * 2
template <int N, int K, int BM, int BN, int BK, int EPI>
__global__ __launch_bounds__(256) void gemm_kernel(const u16* __restrict__ A,
                                                   const u16* __restrict__ Bt,
                                                   const float* __restrict__ bias,
                                                   const u16* __restrict__ aux,
                                                   u16* __restrict__ Out) {
  constexpr int WCOL = (BN >= 128) ? 2 : 1;
  constexpr int WROW = 4 / WCOL;
  constexpr int MF = (BM / WROW) / 16;
  constexpr int NF = (BN / WCOL) / 16;
  constexpr int NT = K / BK;
  constexpr int KS = BK / 32;        // MFMA k-substeps per staged tile
  constexpr int RPP = 2048 / BK;     // rows per staging pass

  __shared__ u16 lA[2][BM * BK];
  __shared__ u16 lB[2][BN * BK];

  const int tid = threadIdx.x;
  const int w = tid >> 6;
  const int lane = tid & 63;
  const int l15 = lane & 15, hi = lane >> 4;
  const int wr = w / WCOL, wc = w % WCOL;
  const int m0 = blockIdx.y * BM, n0 = blockIdx.x * BN;

  f32x4 acc[MF][NF];
#pragma unroll
  for (int m = 0; m < MF; m++)
#pragma unroll
    for (int n = 0; n < NF; n++) acc[m][n] = (f32x4){0.f, 0.f, 0.f, 0.f};

  const int srow = tid / (BK / 8);       // staging row within pass
  const int sc8 = (tid % (BK / 8)) * 8;  // k sub-offset (elements)

  auto stage = [&](int buf, int t) {
    const u16* Ab = A + (long)m0 * K + t * BK;
    const u16* Bb = Bt + (long)n0 * K + t * BK;
#pragma unroll
    for (int i = 0; i < BM / RPP; i++)
      gll16(Ab + (long)(i * RPP + srow) * K + sc8, &lA[buf][i * 2048 + w * 512]);
#pragma unroll
    for (int i = 0; i < BN / RPP; i++)
      gll16(Bb + (long)(i * RPP + srow) * K + sc8, &lB[buf][i * 2048 + w * 512]);
  };

  stage(0, 0);
  __syncthreads();

#pragma unroll 2
  for (int t = 0; t < NT; t++) {
    int buf = t & 1;
    if (t + 1 < NT) stage(buf ^ 1, t + 1);
    s16x8 af[MF][KS], bf[NF][KS];
#pragma unroll
    for (int m = 0; m < MF; m++)
#pragma unroll
      for (int ks = 0; ks < KS; ks++)
        af[m][ks] = *reinterpret_cast<const s16x8*>(
            &lA[buf][(wr * (MF * 16) + m * 16 + l15) * BK + ks * 32 + hi * 8]);
#pragma unroll
    for (int n = 0; n < NF; n++)
#pragma unroll
      for (int ks = 0; ks < KS; ks++)
        bf[n][ks] = *reinterpret_cast<const s16x8*>(
            &lB[buf][(wc * (NF * 16) + n * 16 + l15) * BK + ks * 32 + hi * 8]);
#pragma unroll
    for (int ks = 0; ks < KS; ks++)
#pragma unroll
      for (int m = 0; m < MF; m++)
#pragma unroll
        for (int n = 0; n < NF; n++)
          acc[m][n] = __builtin_amdgcn_mfma_f32_16x16x32_bf16(af[m][ks], bf[n][ks], acc[m][n], 0, 0, 0);
    __syncthreads();
  }

#pragma unroll
  for (int n = 0; n < NF; n++) {
    int col = n0 + wc * (NF * 16) + n * 16 + l15;
    float bs = bias[col];
#pragma unroll
    for (int m = 0; m < MF; m++) {
      int rbase = m0 + wr * (MF * 16) + m * 16 + hi * 4;
#pragma unroll
      for (int j = 0; j < 4; j++) {
        int row = rbase + j;
        float z = acc[m][n][j] + bs;
        float o;
        if (EPI == 0) {
          o = z / (1.f + __expf(-z));               // silu
        } else {
          float gs = 1.f / (1.f + __expf(-z));      // sigmoid
          float xv = bf2f(aux[(long)row * N + col]);
          o = xv * gs * 2.f;
        }
        Out[(long)row * N + col] = f2bf(o);
      }
    }
  }
}

// ---------------- K4: per-token proj (K=192) + fused LayerNorm ---------------
// Tiled GEMM: BM=64 rows x BN=512 cols (full LN row), BK=32 double-buffered,
// 512 threads = 8 waves as 2M x 4N. Wave tile 32x128 (MF=2, NF=8).
// Both operands staged via global_load_lds (coalesced). LN fused in epilogue.
__global__ __launch_bounds__(512) void proj_ln_kernel(const u16* __restrict__ xb,
                                                      const u16* __restrict__ pwt,
                                                      const float* __restrict__ pb,
                                                      const float* __restrict__ lng,
                                                      const float* __restrict__ lnb,
                                                      float* __restrict__ out) {
  __shared__ u16 lA[2][64 * 32];    //  8 KB
  __shared__ u16 lB[2][512 * 32];   // 64 KB
  __shared__ float sred[64][4][2];  //  2 KB  [row][n-wave][sum,sumsq]

  const int t = blockIdx.y;
  const int m0 = blockIdx.x * 64;
  const int tid = threadIdx.x;
  const int w = tid >> 6, lane = tid & 63;
  const int l15 = lane & 15, hi = lane >> 4;
  const int wr = w >> 2, wc = w & 3;    // 2M x 4N

  const u16* Ab = xb + (long)m0 * TOTAL + t * CHUNKC;   // row stride TOTAL
  const u16* Bb = pwt + (long)t * DMOD * CHUNKC;        // row stride CHUNKC

  const int srow = tid >> 2;       // 0..127
  const int sc8 = (tid & 3) * 8;

  auto stage = [&](int buf, int kt) {
    if (w < 4)  // A tile: 64 rows x 32 k = 256 chunks of 16B (waves 0-3)
      gll16(Ab + (long)srow * TOTAL + kt * 32 + sc8, &lA[buf][w * 512]);
#pragma unroll
    for (int i = 0; i < 4; i++)  // B tile: 512 rows x 32 k
      gll16(Bb + (long)(i * 128 + srow) * CHUNKC + kt * 32 + sc8,
            &lB[buf][i * 4096 + w * 512]);
  };

  f32x4 acc[2][8];
#pragma unroll
  for (int m = 0; m < 2; m++)
#pragma unroll
    for (int n = 0; n < 8; n++) acc[m][n] = (f32x4){0.f, 0.f, 0.f, 0.f};

  stage(0, 0);
  __syncthreads();

#pragma unroll
  for (int kt = 0; kt < 6; kt++) {
    int buf = kt & 1;
    if (kt + 1 < 6) stage(buf ^ 1, kt + 1);
    s16x8 af[2], bfr[8];
#pragma unroll
    for (int m = 0; m < 2; m++)
      af[m] = *reinterpret_cast<const s16x8*>(&lA[buf][(wr * 32 + m * 16 + l15) * 32 + hi * 8]);
#pragma unroll
    for (int n = 0; n < 8; n++)
      bfr[n] = *reinterpret_cast<const s16x8*>(&lB[buf][(wc * 128 + n * 16 + l15) * 32 + hi * 8]);
#pragma unroll
    for (int m = 0; m < 2; m++)
#pragma unroll
      for (int n = 0; n < 8; n++)
        acc[m][n] = __builtin_amdgcn_mfma_f32_16x16x32_bf16(af[m], bfr[n], acc[m][n], 0, 0, 0);
    __syncthreads();
  }

  // bias + per-row partial stats; lane owns rows r = wr*32 + m*16 + hi*4 + j
  float sum[2][4], sq[2][4];
#pragma unroll
  for (int m = 0; m < 2; m++)
#pragma unroll
    for (int j = 0; j < 4; j++) { sum[m][j] = 0.f; sq[m][j] = 0.f; }

#pragma unroll
  for (int n = 0; n < 8; n++) {
    float bs = pb[t * DMOD + wc * 128 + n * 16 + l15];
#pragma unroll
    for (int m = 0; m < 2; m++)
#pragma unroll
      for (int j = 0; j < 4; j++) {
        float v = acc[m][n][j] + bs;
        acc[m][n][j] = v;
        sum[m][j] += v;
        sq[m][j] += v * v;
      }
  }
#pragma unroll
  for (int m = 0; m < 2; m++)
#pragma unroll
    for (int j = 0; j < 4; j++) {
#pragma unroll
      for (int o = 1; o < 16; o <<= 1) {
        sum[m][j] += __shfl_xor(sum[m][j], o, 64);
        sq[m][j] += __shfl_xor(sq[m][j], o, 64);
      }
    }
  if (l15 == 0) {
#pragma unroll
    for (int m = 0; m < 2; m++)
#pragma unroll
      for (int j = 0; j < 4; j++) {
        int r = wr * 32 + m * 16 + hi * 4 + j;
        sred[r][wc][0] = sum[m][j];
        sred[r][wc][1] = sq[m][j];
      }
  }
  __syncthreads();

  float mean[2][4], rstd[2][4];
#pragma unroll
  for (int m = 0; m < 2; m++)
#pragma unroll
    for (int j = 0; j < 4; j++) {
      int r = wr * 32 + m * 16 + hi * 4 + j;
      float s = sred[r][0][0] + sred[r][1][0] + sred[r][2][0] + sred[r][3][0];
      float q = sred[r][0][1] + sred[r][1][1] + sred[r][2][1] + sred[r][3][1];
      float mu = s * (1.f / 512.f);
      float var = q * (1.f / 512.f) - mu * mu;
      mean[m][j] = mu;
      rstd[m][j] = rsqrtf(var + 1e-5f);
    }
#pragma unroll
  for (int n = 0; n < 8; n++) {
    int c = wc * 128 + n * 16 + l15;
    float g = lng[t * DMOD + c], bb = lnb[t * DMOD + c];
#pragma unroll
    for (int m = 0; m < 2; m++)
#pragma unroll
      for (int j = 0; j < 4; j++) {
        int r = wr * 32 + m * 16 + hi * 4 + j;
        float o = (acc[m][n][j] - mean[m][j]) * rstd[m][j] * g + bb;
        out[((long)(m0 + r) * TT + t) * DMOD + c] = o;
      }
  }
}

// -----------------------------------------------------------------------------
extern "C" void kernel_launch(void* const* d_in, const int* in_sizes, int n_in,
                              void* d_out, int out_size, void* d_ws, size_t ws_size,
                              hipStream_t stream) {
  const int* feats = (const int*)d_in[0];
  const float* embS = (const float*)d_in[1];
  const float* embM = (const float*)d_in[2];
  const float* w1 = (const float*)d_in[3];
  const float* b1 = (const float*)d_in[4];
  const float* w2 = (const float*)d_in[5];
  const float* b2 = (const float*)d_in[6];
  const float* pw = (const float*)d_in[7];
  const float* pb = (const float*)d_in[8];
  const float* lng = (const float*)d_in[9];
  const float* lnb = (const float*)d_in[10];
  float* out = (float*)d_out;

  char* p = (char*)d_ws;
  u16* catb = (u16*)p; p += (size_t)4096 * 3072 * 2;   // 25.2 MB
  u16* hb   = (u16*)p; p += (size_t)4096 * 768 * 2;    //  6.3 MB
  u16* xb   = (u16*)p; p += (size_t)4096 * 3072 * 2;   // 25.2 MB
  u16* w1t  = (u16*)p; p += (size_t)768 * 3072 * 2;    //  4.7 MB
  u16* w2t  = (u16*)p; p += (size_t)3072 * 768 * 2;    //  4.7 MB
  u16* pwt  = (u16*)p; p += (size_t)16 * 512 * 192 * 2;//  3.1 MB  (total ~69 MB)

  // K0: all weight transposes (re-run every call: ws is re-poisoned)
  transpose_all_kernel<<<6144, dim3(32, 8), 0, stream>>>(w1, w1t, w2, w2t, pw, pwt);

  // K1: embedding + pooling
  embed_kernel<<<4096, 256, 0, stream>>>(feats, embS, embM, catb);

  // K2: h = silu(cat @ w1 + b1)    M=4096 N=768 K=3072, BK=64 -> 768 blocks (3/CU)
  gemm_kernel<768, 3072, 64, 64, 64, 0><<<dim3(768 / 64, 4096 / 64), 256, 0, stream>>>(
      catb, w1t, b1, nullptr, hb);

  // K3: x = cat * sigmoid(h @ w2 + b2)   M=4096 N=3072 K=768, BK=32 -> 768 blocks (3/CU)
  gemm_kernel<3072, 768, 128, 128, 32, 1><<<dim3(3072 / 128, 4096 / 128), 256, 0, stream>>>(
      hb, w2t, b2, catb, xb);

  // K4: per-token proj + LN  (64 rows x full 512-col row per block) -> 1024 blocks
  proj_ln_kernel<<<dim3(4096 / 64, 16), 512, 0, stream>>>(xb, pwt, pb, lng, lnb, out);
}